// Round 12
// baseline (43.746 us; speedup 1.0000x reference)
//
#include <hip/hip_runtime.h>

#define NC      16
#define HW      (512 * 512)
#define NB      8
#define BPB     128                       // blocks per batch
#define NBLK    (NB * BPB)                // 1024 blocks
#define THREADS 256
#define PXR     256                       // pixels per round
#define ROUNDS  8                         // 2048 px per block
#define SMOOTH  1e-5f

// Partials in d_ws, SoA: P[v * NBLK + blk], v in [0,34):
//   v=0..15 inter[c] (batch b=blk/BPB), v=16..31 denom[c], v=32 ce, v=33 pen.
// Every slot overwritten every launch -> no zeroing, no atomics.
//
// r9/r10/r11 lesson: all drain-per-round schedules plateau at ~4.3 TB/s.
// __syncthreads() = s_waitcnt vmcnt(0) + s_barrier -> in-flight collapses to
// zero every round (latency-capped, Little's law). This version: T3/T4
// counted vmcnt. 3-deep LDS buffers; per round each wave keeps 2 future
// rounds (10 DMA instrs) outstanding ACROSS a raw s_barrier; waits are
// vmcnt(5), never 0, until the last round. Targets staged via DMA too, so
// no register dependence lets the compiler insert a vmcnt(0).
typedef __attribute__((address_space(3))) unsigned int       lds_u32;
typedef __attribute__((address_space(1))) const unsigned int glb_u32;

__device__ __forceinline__ void stage16(const float* g, float* l) {
    // lane i: 16B from g+16B*i -> lds_base + 16B*i (wave-uniform l, linear)
    __builtin_amdgcn_global_load_lds((glb_u32*)(const void*)g,
                                     (lds_u32*)(void*)l, 16, 0, 0);
}
__device__ __forceinline__ void stage4(const int* g, int* l) {
    __builtin_amdgcn_global_load_lds((glb_u32*)(const void*)g,
                                     (lds_u32*)(void*)l, 4, 0, 0);
}

__global__ __launch_bounds__(THREADS) void domino_main(
    const float* __restrict__ logits,   // [B, C, H, W]
    const int*   __restrict__ tgt,      // [B, H, W]
    const float* __restrict__ penalty,  // [C, C] row = target class
    float*       __restrict__ P)
{
    __shared__ float buf[3][NC * PXR];  // 3 x 16 KB, class-major buf[s][c*PXR+p]
    __shared__ int   tbuf[3][PXR];      // 3 x 1 KB
    __shared__ float pen_t[NC * NC];    // pen_t[c*NC+t] = penalty[t*NC+c]
    __shared__ float red[4][34];

    const int tid  = threadIdx.x;
    const int w    = tid >> 6;          // wave 0..3: stages classes 4w..4w+3
    const int lane = tid & 63;
    const int b    = blockIdx.x / BPB;
    const int blk  = blockIdx.x % BPB;

    // pen_t via normal load (transposed write; once, before the pipeline).
    {
        const int r = tid / NC, c = tid % NC;
        pen_t[c * NC + r] = penalty[tid];
    }

    const float* ob   = logits + (size_t)b * NC * HW;
    const int*   tb   = tgt    + (size_t)b * HW;
    const int    base = blk * (ROUNDS * PXR);

    // Wave w: 4 classes x 1KB contiguous + its 256B target chunk = 5 vmem ops.
#define ISSUE(RR, SLOT) do {                                                   \
        const int off = base + (RR) * PXR;                                     \
        float* const dst = &buf[(SLOT)][0];                                    \
        stage16(ob + (size_t)(4*w+0) * HW + off + lane * 4, dst + (4*w+0) * PXR); \
        stage16(ob + (size_t)(4*w+1) * HW + off + lane * 4, dst + (4*w+1) * PXR); \
        stage16(ob + (size_t)(4*w+2) * HW + off + lane * 4, dst + (4*w+2) * PXR); \
        stage16(ob + (size_t)(4*w+3) * HW + off + lane * 4, dst + (4*w+3) * PXR); \
        stage4(tb + off + w * 64 + lane, &tbuf[(SLOT)][w * 64]);               \
    } while (0)

    ISSUE(0, 0);                        // prologue: rounds 0 and 1 in flight
    ISSUE(1, 1);

    float inter_acc[NC], denom_acc[NC];
#pragma unroll
    for (int c = 0; c < NC; ++c) { inter_acc[c] = 0.f; denom_acc[c] = 0.f; }
    float ce_acc = 0.f, pen_acc = 0.f;

#pragma unroll
    for (int r = 0; r < ROUNDS; ++r) {
        // 1) Counted wait: own round-r loads retired (in-order retirement;
        //    the 5 newest are round r+1's). Never vmcnt(0) until last round.
        if (r < ROUNDS - 1)
            asm volatile("s_waitcnt vmcnt(5) lgkmcnt(0)" ::: "memory");
        else
            asm volatile("s_waitcnt vmcnt(0) lgkmcnt(0)" ::: "memory");
        __builtin_amdgcn_sched_barrier(0);
        // 2) Raw barrier: ALL waves' round-r loads landed; all waves done
        //    reading slot (r-1)%3 (their compute r-1 precedes this barrier).
        __builtin_amdgcn_s_barrier();
        __builtin_amdgcn_sched_barrier(0);
        // 3) Refill the freed slot ((r+2)%3 == (r-1)%3) for round r+2.
        if (r + 2 < ROUNDS) ISSUE(r + 2, (r + 2) % 3);

        // 4) Compute round r: pixel p = tid from LDS.
        //    buf[s][c*PXR+tid]: bank = tid%32 for every c -> conflict-free.
        {
            const float* const cb = &buf[r % 3][0];
            const int t = tbuf[r % 3][tid];
            float e[NC], s = 0.f;
#pragma unroll
            for (int c = 0; c < NC; ++c) {
                e[c] = __expf(cb[c * PXR + tid]);
                s += e[c];
            }
            float et = 0.f;
#pragma unroll
            for (int c = 0; c < NC; ++c) et = (t == c) ? e[c] : et;
            const float inv = 1.0f / s;
            ce_acc -= __logf(et * inv);
            float pdot = 0.f;
#pragma unroll
            for (int c = 0; c < NC; ++c) {
                const float p = e[c] * inv;
                denom_acc[c] += p + ((t == c) ? 1.f : 0.f);
                inter_acc[c] += (t == c) ? p : 0.f;
                pdot += pen_t[c * NC + t] * p;
            }
            pen_acc += pdot;
        }
    }
#undef ISSUE

    // Intra-wave butterfly reductions (64 lanes), then 4-wave fan-in.
#pragma unroll
    for (int c = 0; c < NC; ++c) {
#pragma unroll
        for (int off = 32; off; off >>= 1) {
            inter_acc[c] += __shfl_xor(inter_acc[c], off);
            denom_acc[c] += __shfl_xor(denom_acc[c], off);
        }
    }
#pragma unroll
    for (int off = 32; off; off >>= 1) {
        ce_acc  += __shfl_xor(ce_acc,  off);
        pen_acc += __shfl_xor(pen_acc, off);
    }

    if (lane == 0) {
#pragma unroll
        for (int c = 0; c < NC; ++c) {
            red[w][c]      = inter_acc[c];
            red[w][NC + c] = denom_acc[c];
        }
        red[w][32] = ce_acc;
        red[w][33] = pen_acc;
    }
    __syncthreads();                    // full drain: pipeline is done anyway

    if (tid < 34) {
        const float v = red[0][tid] + red[1][tid] + red[2][tid] + red[3][tid];
        P[tid * NBLK + blockIdx.x] = v;
    }
}

// One block, 1024 threads: 8 threads per (c,b) dice bin (each sums 16 of the
// 128 per-batch partials), plus full-width ce/pen reduction. Single pass.
__global__ __launch_bounds__(1024) void domino_final(
    const float* __restrict__ P, float* __restrict__ out)
{
    __shared__ float dice_l[128], ce_l[16], pen_l[16];

    const int tid = threadIdx.x;
    const int bin = tid >> 3, j = tid & 7;   // bin in [0,128)
    const int c = bin >> 3, bb = bin & 7;

    const float4* ip = (const float4*)(P + (size_t)c        * NBLK + bb * BPB) + j * 4;
    const float4* dp = (const float4*)(P + (size_t)(NC + c) * NBLK + bb * BPB) + j * 4;
    float inter = 0.f, denom = 0.f;
#pragma unroll
    for (int k = 0; k < 4; ++k) {
        const float4 a = ip[k]; inter += a.x + a.y + a.z + a.w;
        const float4 d = dp[k]; denom += d.x + d.y + d.z + d.w;
    }
#pragma unroll
    for (int off = 4; off; off >>= 1) {      // reduce the 8-thread group
        inter += __shfl_xor(inter, off);
        denom += __shfl_xor(denom, off);
    }
    if (j == 0)
        dice_l[bin] = 1.0f - (2.0f * inter + SMOOTH) / (denom + SMOOTH);

    float ce  = P[32 * NBLK + tid];          // NBLK == 1024 == blockDim
    float pen = P[33 * NBLK + tid];
#pragma unroll
    for (int off = 32; off; off >>= 1) {
        ce  += __shfl_xor(ce,  off);
        pen += __shfl_xor(pen, off);
    }
    const int lane = tid & 63, wid = tid >> 6;
    if (lane == 0) { ce_l[wid] = ce; pen_l[wid] = pen; }
    __syncthreads();

    if (tid < 64) {
        float d = dice_l[tid] + dice_l[tid + 64];
#pragma unroll
        for (int off = 32; off; off >>= 1) d += __shfl_xor(d, off);
        if (tid == 0) {
            float ces = 0.f, pens = 0.f;
#pragma unroll
            for (int i = 0; i < 16; ++i) { ces += ce_l[i]; pens += pen_l[i]; }
            out[0] = ces  * (1.0f / (8.0f * 262144.0f))
                   + d    * (1.0f / 128.0f)
                   + pens * (1.0f / 8.0f);
        }
    }
}

extern "C" void kernel_launch(void* const* d_in, const int* in_sizes, int n_in,
                              void* d_out, int out_size, void* d_ws, size_t ws_size,
                              hipStream_t stream)
{
    const float* logits = (const float*)d_in[0];   // [8,16,512,512] f32
    const int*   tgt    = (const int*)d_in[1];     // [8,1,512,512] int32
    const float* pen    = (const float*)d_in[2];   // [16,16] f32
    float*       P      = (float*)d_ws;
    float*       out    = (float*)d_out;

    domino_main<<<NBLK, THREADS, 0, stream>>>(logits, tgt, pen, P);
    domino_final<<<1, 1024, 0, stream>>>(P, out);
}